// Round 2
// baseline (374.454 us; speedup 1.0000x reference)
//
#include <hip/hip_runtime.h>
#include <math.h>

#define NROWS   65536
#define NC      1000
#define NTH     21
#define K1_BLKS (NROWS / 4)      // 16384 blocks, 4 rows (waves) each
#define H_BLKS  64               // histogram blocks
#define NBINS   22               // thresholds 0..20 + "never certain"
// ws layout (floats):
//   unc[NROWS] | conf_signed[NROWS] | pmin[K1_BLKS] | pmax[K1_BLKS] | pce[K1_BLKS]
//   | hist[H_BLKS * 4*NBINS]

__device__ __forceinline__ void upd_max(float v, int i, float& m, int& mi) {
    if (v > m) { m = v; mi = i; }
}

__global__ __launch_bounds__(256) void k1_rowstats(
        const float* __restrict__ logits, const int* __restrict__ labels,
        float* __restrict__ unc_o, float* __restrict__ confs_o,
        float* __restrict__ pmin, float* __restrict__ pmax, float* __restrict__ pce)
{
    const int wave = threadIdx.x >> 6;
    const int lane = threadIdx.x & 63;
    const int row  = (blockIdx.x << 2) + wave;
    const float4* rp = (const float4*)(logits + (size_t)row * NC);

    // 250 float4 per row; lane handles f4 indices lane, lane+64, lane+128, lane+192
    float4 r0 = rp[lane];
    float4 r1 = rp[lane + 64];
    float4 r2 = rp[lane + 128];
    float4 r3 = make_float4(-1e30f, -1e30f, -1e30f, -1e30f);
    if (lane < 250 - 192) r3 = rp[lane + 192];

    // local max + argmax (increasing index order => first-occurrence tie-break)
    float m = -1e30f; int mi = 0;
    int b0 = lane << 2;
    upd_max(r0.x, b0 + 0, m, mi); upd_max(r0.y, b0 + 1, m, mi);
    upd_max(r0.z, b0 + 2, m, mi); upd_max(r0.w, b0 + 3, m, mi);
    int b1 = (lane + 64) << 2;
    upd_max(r1.x, b1 + 0, m, mi); upd_max(r1.y, b1 + 1, m, mi);
    upd_max(r1.z, b1 + 2, m, mi); upd_max(r1.w, b1 + 3, m, mi);
    int b2 = (lane + 128) << 2;
    upd_max(r2.x, b2 + 0, m, mi); upd_max(r2.y, b2 + 1, m, mi);
    upd_max(r2.z, b2 + 2, m, mi); upd_max(r2.w, b2 + 3, m, mi);
    int b3 = (lane + 192) << 2;
    upd_max(r3.x, b3 + 0, m, mi); upd_max(r3.y, b3 + 1, m, mi);
    upd_max(r3.z, b3 + 2, m, mi); upd_max(r3.w, b3 + 3, m, mi);

    #pragma unroll
    for (int off = 1; off < 64; off <<= 1) {
        float om = __shfl_xor(m, off, 64);
        int   oi = __shfl_xor(mi, off, 64);
        if (om > m || (om == m && oi < mi)) { m = om; mi = oi; }
    }

    // exp sums; sentinel -1e30 underflows exp to 0; 0*(-1e30) via fma = -0 (no NaN)
    float se = 0.f, sx = 0.f;
#define ACCUM(v) { float t_ = (v) - m; float e_ = __expf(t_); se += e_; sx = fmaf(e_, t_, sx); }
    ACCUM(r0.x) ACCUM(r0.y) ACCUM(r0.z) ACCUM(r0.w)
    ACCUM(r1.x) ACCUM(r1.y) ACCUM(r1.z) ACCUM(r1.w)
    ACCUM(r2.x) ACCUM(r2.y) ACCUM(r2.z) ACCUM(r2.w)
    ACCUM(r3.x) ACCUM(r3.y) ACCUM(r3.z) ACCUM(r3.w)
#undef ACCUM
    #pragma unroll
    for (int off = 1; off < 64; off <<= 1) {
        se += __shfl_xor(se, off, 64);
        sx += __shfl_xor(sx, off, 64);
    }

    float Z    = se;
    float logZ = logf(Z);
    float conf = 1.0f / Z;            // max prob = exp(m-m)/Z
    float uncv = logZ - sx / Z;       // entropy

    int label = labels[row];          // wave-uniform scalar load
    int f4 = label >> 2, slot = label & 3, it = f4 >> 6;
    float4 q = (it == 0) ? r0 : (it == 1) ? r1 : (it == 2) ? r2 : r3;
    float cand = (slot == 0) ? q.x : (slot == 1) ? q.y : (slot == 2) ? q.z : q.w;
    float xl = __shfl(cand, f4 & 63, 64);
    float logp = (xl - m) - logZ;

    __shared__ float s_u[4], s_lp[4];
    if (lane == 0) {
        unc_o[row]   = uncv;
        confs_o[row] = (mi == label) ? conf : -conf;  // sign carries accuracy bit
        s_u[wave] = uncv; s_lp[wave] = logp;
    }
    __syncthreads();
    if (threadIdx.x == 0) {
        float mn = fminf(fminf(s_u[0], s_u[1]), fminf(s_u[2], s_u[3]));
        float mx = fmaxf(fmaxf(s_u[0], s_u[1]), fmaxf(s_u[2], s_u[3]));
        pmin[blockIdx.x] = mn;
        pmax[blockIdx.x] = mx;
        pce[blockIdx.x]  = s_lp[0] + s_lp[1] + s_lp[2] + s_lp[3];
    }
}

__global__ __launch_bounds__(1024) void k3_hist(
        const float* __restrict__ unc, const float* __restrict__ confs,
        const float* __restrict__ pmin, const float* __restrict__ pmax,
        float* __restrict__ hist)
{
    __shared__ float h[4 * NBINS];
    __shared__ float smn[16], smx[16];
    __shared__ float s_umin, s_umax;
    const int tid  = threadIdx.x;
    const int wave = tid >> 6;
    const int lane = tid & 63;

    // phase A: every block redundantly reduces the 16384 partials (L2-hot)
    float mn = 1e30f, mx = -1e30f;
    #pragma unroll
    for (int t = 0; t < K1_BLKS / 1024; ++t) {
        int i = tid + t * 1024;
        mn = fminf(mn, pmin[i]);
        mx = fmaxf(mx, pmax[i]);
    }
    #pragma unroll
    for (int off = 1; off < 64; off <<= 1) {
        mn = fminf(mn, __shfl_xor(mn, off, 64));
        mx = fmaxf(mx, __shfl_xor(mx, off, 64));
    }
    if (lane == 0) { smn[wave] = mn; smx[wave] = mx; }
    if (tid < 4 * NBINS) h[tid] = 0.f;
    __syncthreads();
    if (tid == 0) {
        float a = 1e30f, b = -1e30f;
        #pragma unroll
        for (int w = 0; w < 16; ++w) { a = fminf(a, smn[w]); b = fmaxf(b, smx[w]); }
        s_umin = a; s_umax = b;
    }
    __syncthreads();
    float umin = s_umin, du = s_umax - s_umin;

    // phase B: one row per thread
    int i = blockIdx.x * 1024 + tid;
    float u  = unc[i];
    float cs = confs[i];
    float conf = fabsf(cs);
    bool  acc  = cs > 0.f;
    float tu = tanhf(u);

    // bucket = smallest t with u <= umin + (t*0.05)*du ; NTH => never certain
    int b = NTH;
    #pragma unroll
    for (int t = NTH - 1; t >= 0; --t) {
        float th = umin + ((float)t * 0.05f) * du;
        if (u <= th) b = t;
    }
    float w = acc ? conf : (1.f - conf);
    int base = acc ? 0 : 2 * NBINS;
    atomicAdd(&h[base + b],         w * (1.f - tu));  // certain side -> n_ac / n_ic
    atomicAdd(&h[base + NBINS + b], w * tu);          // uncertain side -> n_au / n_iu
    __syncthreads();
    if (tid < 4 * NBINS) hist[blockIdx.x * 4 * NBINS + tid] = h[tid];
}

__global__ __launch_bounds__(256) void k4_final(
        const float* __restrict__ pce, const float* __restrict__ hist,
        float* __restrict__ out)
{
    const int tid = threadIdx.x;
    // reduce ce partials
    float s = 0.f;
    for (int i = tid; i < K1_BLKS; i += 256) s += pce[i];
    #pragma unroll
    for (int off = 1; off < 64; off <<= 1) s += __shfl_xor(s, off, 64);
    __shared__ float ss[4];
    if ((tid & 63) == 0) ss[tid >> 6] = s;
    // reduce per-block histograms: bin tid handled by thread tid
    __shared__ float bins[4 * NBINS];
    if (tid < 4 * NBINS) {
        float v = 0.f;
        for (int blk = 0; blk < H_BLKS; ++blk) v += hist[blk * 4 * NBINS + tid];
        bins[tid] = v;
    }
    __syncthreads();
    if (tid == 0) {
        float ce_sum = ss[0] + ss[1] + ss[2] + ss[3];
        float tot_au = 0.f, tot_iu = 0.f;
        for (int b = 0; b < NBINS; ++b) {
            tot_au += bins[NBINS + b];
            tot_iu += bins[3 * NBINS + b];
        }
        float cac = 0.f, cau = 0.f, cic = 0.f, ciu = 0.f;
        float avu[NTH];
        for (int t = 0; t < NTH; ++t) {
            cac += bins[t];
            cau += bins[NBINS + t];
            cic += bins[2 * NBINS + t];
            ciu += bins[3 * NBINS + t];
            float nac = cac, nau = tot_au - cau, nic = cic, niu = tot_iu - ciu;
            avu[t] = (nac + niu) / (nac + nau + nic + niu + 1e-12f);
        }
        float auc = 0.f;
        for (int t = 0; t + 1 < NTH; ++t) auc += 0.5f * (avu[t + 1] + avu[t]) * 0.05f;
        float avu_loss = -3.0f * logf(auc + 1e-12f);
        float ce = -ce_sum / (float)NROWS;
        out[0] = avu_loss + ce;
    }
}

extern "C" void kernel_launch(void* const* d_in, const int* in_sizes, int n_in,
                              void* d_out, int out_size, void* d_ws, size_t ws_size,
                              hipStream_t stream)
{
    const float* logits = (const float*)d_in[0];
    const int*   labels = (const int*)d_in[1];
    float* ws    = (float*)d_ws;
    float* unc   = ws;
    float* confs = unc + NROWS;
    float* pmin  = confs + NROWS;
    float* pmax  = pmin + K1_BLKS;
    float* pce   = pmax + K1_BLKS;
    float* hist  = pce + K1_BLKS;     // H_BLKS * 4*NBINS floats

    hipLaunchKernelGGL(k1_rowstats, dim3(K1_BLKS), dim3(256), 0, stream,
                       logits, labels, unc, confs, pmin, pmax, pce);
    hipLaunchKernelGGL(k3_hist, dim3(H_BLKS), dim3(1024), 0, stream,
                       unc, confs, pmin, pmax, hist);
    hipLaunchKernelGGL(k4_final, dim3(1), dim3(256), 0, stream,
                       pce, hist, (float*)d_out);
}